// Round 2
// baseline (3530.643 us; speedup 1.0000x reference)
//
#include <hip/hip_runtime.h>
#include <cstdint>
#include <cstddef>

// Problem constants (ViTDet block, B=4, 64x64, DIM=768, 14x14 windows)
#define NIMG   4
#define GRIDSZ 64          // H = W = 64
#define CH     768
#define NHEAD  12
#define WSZ    14
#define NWINS  100         // 4 images * 5*5 windows
#define NTOK   196         // 14*14
#define MWIN   19600       // NWINS*NTOK
#define MREAL  16384       // 4*64*64
#define MLPC   3072
#define QKSCALE 0.125f

typedef unsigned short u16;

__device__ __forceinline__ float b2f(u16 u) {
  uint32_t x = (uint32_t)u << 16; float f; __builtin_memcpy(&f, &x, 4); return f;
}
__device__ __forceinline__ u16 f2b(float f) {
  uint32_t x; __builtin_memcpy(&x, &f, 4);
  x += 0x7fffu + ((x >> 16) & 1u);           // round-to-nearest-even
  return (u16)(x >> 16);
}

// ---------------------------------------------------------------------------
// Transpose NCHW -> NHWC  (f32 -> f32), 32x32 LDS tiles
// ---------------------------------------------------------------------------
__global__ __launch_bounds__(256) void k_nchw2nhwc(const float* __restrict__ in,
                                                   float* __restrict__ out) {
  __shared__ float tile[32][33];
  int b  = blockIdx.z;
  int g0 = blockIdx.x * 32;
  int c0 = blockIdx.y * 32;
  int tx = threadIdx.x, ty = threadIdx.y;  // 32 x 8
  const float* ip = in + (size_t)b * CH * 4096;
  float* op = out + (size_t)b * 4096 * CH;
#pragma unroll
  for (int k = 0; k < 32; k += 8)
    tile[ty + k][tx] = ip[(size_t)(c0 + ty + k) * 4096 + g0 + tx];
  __syncthreads();
#pragma unroll
  for (int k = 0; k < 32; k += 8)
    op[(size_t)(g0 + ty + k) * CH + c0 + tx] = tile[tx][ty + k];
}

__global__ __launch_bounds__(256) void k_nhwc2nchw(const float* __restrict__ in,
                                                   float* __restrict__ out) {
  __shared__ float tile[32][33];
  int b  = blockIdx.z;
  int g0 = blockIdx.x * 32;
  int c0 = blockIdx.y * 32;
  int tx = threadIdx.x, ty = threadIdx.y;
  const float* ip = in + (size_t)b * 4096 * CH;
  float* op = out + (size_t)b * CH * 4096;
#pragma unroll
  for (int k = 0; k < 32; k += 8)
    tile[ty + k][tx] = ip[(size_t)(g0 + ty + k) * CH + c0 + tx];
  __syncthreads();
#pragma unroll
  for (int k = 0; k < 32; k += 8)
    op[(size_t)(c0 + ty + k) * 4096 + g0 + tx] = tile[tx][ty + k];
}

// ---------------------------------------------------------------------------
// LayerNorm over 768 channels (f32 in, bf16 out). One 256-thr block per row.
// window_mode: scatter to window-partitioned slot (attention input layout)
// ---------------------------------------------------------------------------
__device__ __forceinline__ float block_sum(float s, float* red) {
  __syncthreads();
#pragma unroll
  for (int off = 32; off > 0; off >>= 1) s += __shfl_down(s, off, 64);
  int wid = threadIdx.x >> 6, lane = threadIdx.x & 63;
  if (lane == 0) red[wid] = s;
  __syncthreads();
  return red[0] + red[1] + red[2] + red[3];
}

__global__ __launch_bounds__(256) void k_ln(const float* __restrict__ x,
                                            const float* __restrict__ wt,
                                            const float* __restrict__ bs,
                                            u16* __restrict__ y,
                                            int window_mode) {
  __shared__ float red[4];
  int row = blockIdx.x, tid = threadIdx.x;
  const float* xp = x + (size_t)row * CH;
  float v0 = xp[tid], v1 = xp[tid + 256], v2 = xp[tid + 512];
  float mu = block_sum(v0 + v1 + v2, red) * (1.0f / 768.0f);
  float d0 = v0 - mu, d1 = v1 - mu, d2 = v2 - mu;
  float var = block_sum(d0 * d0 + d1 * d1 + d2 * d2, red) * (1.0f / 768.0f);
  float rs = rsqrtf(var + 1e-6f);
  int orow = row;
  if (window_mode) {
    int b = row >> 12, hw = row & 4095;
    int h = hw >> 6, wc = hw & 63;
    orow = (b * 25 + (h / WSZ) * 5 + (wc / WSZ)) * NTOK + (h % WSZ) * WSZ + (wc % WSZ);
  }
  u16* yp = y + (size_t)orow * CH;
  yp[tid]       = f2b(d0 * rs * wt[tid]       + bs[tid]);
  yp[tid + 256] = f2b(d1 * rs * wt[tid + 256] + bs[tid + 256]);
  yp[tid + 512] = f2b(d2 * rs * wt[tid + 512] + bs[tid + 512]);
}

// ---------------------------------------------------------------------------
// SGEMM: C = act(A[MxK](bf16) @ B[KxN](f32) + bias)
// BM=BN=128, BK=8, 256 threads, 8x8 microtile, fp32 accumulate.
// mode 0: C bf16 store           mode 1: C f32 +=
// mode 2: window-unpartition f32 += (skip pad rows); abs row = row + row0
// act 1: exact GELU
// ---------------------------------------------------------------------------
__global__ __launch_bounds__(256) void k_gemm(const u16* __restrict__ A,
                                              const float* __restrict__ B,
                                              const float* __restrict__ bias,
                                              void* __restrict__ Cv,
                                              int M, int N, int K,
                                              int act, int mode, int row0) {
  __shared__ float As[8][128];
  __shared__ float Bs[8][128];
  int tid = threadIdx.x;
  int bn = blockIdx.x, bm = blockIdx.y;
  int arow = tid >> 1;
  int acol = (tid & 1) << 2;
  int brow = tid >> 5;
  int bcol = (tid & 31) << 2;
  int trow = (tid >> 4) << 3;
  int tcol = (tid & 15) << 3;

  float acc[8][8];
#pragma unroll
  for (int i = 0; i < 8; i++)
#pragma unroll
    for (int j = 0; j < 8; j++) acc[i][j] = 0.0f;

  int gArow = bm * 128 + arow;
  bool aval = gArow < M;
  int crow = aval ? gArow : (M - 1);
  const u16* Ap = A + (size_t)crow * K + acol;
  const float* Bp = B + (size_t)brow * N + bn * 128 + bcol;

  for (int k0 = 0; k0 < K; k0 += 8) {
    ushort4 av = aval ? *(const ushort4*)(Ap + k0) : make_ushort4(0, 0, 0, 0);
    float4 bv = *(const float4*)(Bp);
    Bp += (size_t)8 * N;
    __syncthreads();
    As[acol + 0][arow] = b2f(av.x);
    As[acol + 1][arow] = b2f(av.y);
    As[acol + 2][arow] = b2f(av.z);
    As[acol + 3][arow] = b2f(av.w);
    *(float4*)&Bs[brow][bcol] = bv;
    __syncthreads();
#pragma unroll
    for (int kk = 0; kk < 8; kk++) {
      float a[8], bb[8];
#pragma unroll
      for (int i = 0; i < 8; i++) a[i] = As[kk][trow + i];
#pragma unroll
      for (int j = 0; j < 8; j++) bb[j] = Bs[kk][tcol + j];
#pragma unroll
      for (int i = 0; i < 8; i++)
#pragma unroll
        for (int j = 0; j < 8; j++) acc[i][j] += a[i] * bb[j];
    }
  }

#pragma unroll
  for (int i = 0; i < 8; i++) {
    int row = bm * 128 + trow + i;
    if (row >= M) continue;
    size_t gbase = 0;
    bool valid = true;
    if (mode == 2) {  // window slot -> image token
      int rowa = row + row0;
      int widx = rowa / NTOK, tt = rowa % NTOK;
      int b = widx / 25, wq = widx % 25;
      int h = (wq / 5) * WSZ + tt / WSZ;
      int w = (wq % 5) * WSZ + tt % WSZ;
      valid = (h < GRIDSZ) && (w < GRIDSZ);
      if (valid) gbase = ((size_t)((b * GRIDSZ + h) * GRIDSZ + w)) * CH;
    }
#pragma unroll
    for (int j = 0; j < 8; j++) {
      int col = bn * 128 + tcol + j;
      float v = acc[i][j] + bias[col];
      if (act == 1) v = 0.5f * v * (1.0f + erff(v * 0.70710678118654752440f));
      if (mode == 0)      ((u16*)Cv)[(size_t)row * N + col] = f2b(v);
      else if (mode == 1) ((float*)Cv)[(size_t)row * N + col] += v;
      else if (valid)     ((float*)Cv)[gbase + col] += v;
    }
  }
}

// ---------------------------------------------------------------------------
// Windowed attention: one block per (head, local window). qkv is bf16
// (chunk-local base), output bf16 at absolute window index win0+blockIdx.y.
// Decomposed rel-pos from UNSCALED q; exp-sum softmax (scores bounded).
// ---------------------------------------------------------------------------
#define KTILE 49
#define RSTR  15
__global__ __launch_bounds__(256) void k_attn(const u16* __restrict__ qkv,
                                              const float* __restrict__ rel_h,
                                              const float* __restrict__ rel_w,
                                              u16* __restrict__ out, int win0) {
  __shared__ float Ks[KTILE * 64];
  __shared__ float Vs[KTILE * 64];
  __shared__ float rhs[NTOK * RSTR];
  __shared__ float rws[NTOK * RSTR];
  int head = blockIdx.x;
  int wloc = blockIdx.y;
  int tid  = threadIdx.x;
  size_t base = (size_t)wloc * NTOK * (3 * CH);
  int hoff = head * 64;

  float q[64];
  float o[64];
  float l = 0.0f;
  if (tid < NTOK) {
    const u16* qp = qkv + base + (size_t)tid * (3 * CH) + hoff;
#pragma unroll
    for (int d = 0; d < 64; d += 4) {
      ushort4 u4 = *(const ushort4*)(qp + d);
      q[d] = b2f(u4.x); q[d + 1] = b2f(u4.y); q[d + 2] = b2f(u4.z); q[d + 3] = b2f(u4.w);
    }
#pragma unroll
    for (int d = 0; d < 64; d++) o[d] = 0.0f;
    int hq = tid / WSZ, wq = tid % WSZ;
    for (int kk = 0; kk < WSZ; kk++) {
      const float* rh = rel_h + (size_t)(hq - kk + WSZ - 1) * 64;
      const float* rw = rel_w + (size_t)(wq - kk + WSZ - 1) * 64;
      float sh = 0.0f, sw = 0.0f;
#pragma unroll
      for (int d = 0; d < 64; d++) { sh += q[d] * rh[d]; sw += q[d] * rw[d]; }
      rhs[tid * RSTR + kk] = sh;
      rws[tid * RSTR + kk] = sw;
    }
  }

  for (int t = 0; t < 4; t++) {
    __syncthreads();
    for (int idx = tid; idx < KTILE * 64; idx += 256) {
      int j = idx >> 6, d = idx & 63;
      size_t src = base + (size_t)(t * KTILE + j) * (3 * CH) + hoff + d;
      Ks[idx] = b2f(qkv[src + CH]);
      Vs[idx] = b2f(qkv[src + 2 * CH]);
    }
    __syncthreads();
    if (tid < NTOK) {
      for (int jj = 0; jj < KTILE; jj++) {
        int j = t * KTILE + jj;
        int jh = j / WSZ, jw = j % WSZ;
        const float* kp = &Ks[jj * 64];
        float s = 0.0f;
#pragma unroll
        for (int d = 0; d < 64; d++) s += q[d] * kp[d];
        s = s * QKSCALE + rhs[tid * RSTR + jh] + rws[tid * RSTR + jw];
        float p = __expf(s);
        l += p;
        const float* vp = &Vs[jj * 64];
#pragma unroll
        for (int d = 0; d < 64; d++) o[d] += p * vp[d];
      }
    }
  }

  if (tid < NTOK) {
    float inv = 1.0f / l;
    u16* op = out + ((size_t)(win0 + wloc) * NTOK + tid) * CH + hoff;
#pragma unroll
    for (int d = 0; d < 64; d++) op[d] = f2b(o[d] * inv);
  }
}

// ---------------------------------------------------------------------------
extern "C" void kernel_launch(void* const* d_in, const int* in_sizes, int n_in,
                              void* d_out, int out_size, void* d_ws, size_t ws_size,
                              hipStream_t stream) {
  const float* hidden = (const float*)d_in[0];
  const float* ln1_w  = (const float*)d_in[1];
  const float* ln1_b  = (const float*)d_in[2];
  const float* qkv_w  = (const float*)d_in[3];
  const float* qkv_b  = (const float*)d_in[4];
  const float* proj_w = (const float*)d_in[5];
  const float* proj_b = (const float*)d_in[6];
  const float* rel_h  = (const float*)d_in[7];
  const float* rel_w  = (const float*)d_in[8];
  const float* ln2_w  = (const float*)d_in[9];
  const float* ln2_b  = (const float*)d_in[10];
  const float* fc1_w  = (const float*)d_in[11];
  const float* fc1_b  = (const float*)d_in[12];
  const float* fc2_w  = (const float*)d_in[13];
  const float* fc2_b  = (const float*)d_in[14];
  float* out = (float*)d_out;

  // Adaptive workspace layout:
  //   x_nhwc f32 : 12,582,912 elems = 50,331,648 B   (residual accumulator)
  //   R1 bf16    : 19,600*768      = 30,105,600 B   (xln -> attn_out -> y_ln)
  //   R2 bf16    : remainder        (qkv chunks / mlp-hidden chunks)
  // Minimum total ~81.4 MB; >=261.5 MB degenerates to single-pass chunks.
  char* ws = (char*)d_ws;
  float* x_nhwc = (float*)ws;
  u16*   R1     = (u16*)(ws + 50331648);
  u16*   R2     = (u16*)(ws + 50331648 + 30105600);
  size_t r2_bytes = ws_size > (size_t)(50331648 + 30105600)
                  ? ws_size - (size_t)(50331648 + 30105600) : 0;
  size_t r2e = r2_bytes >> 1;  // bf16 elements

  // windows per qkv/attn chunk; rows per mlp chunk (multiple of 128)
  size_t wc_s = r2e / ((size_t)NTOK * 3 * CH);
  int Wc = wc_s >= NWINS ? NWINS : (int)wc_s;
  if (Wc < 1) Wc = 1;
  size_t rc_s = (r2e / MLPC / 128) * 128;
  int Rc = rc_s >= MREAL ? MREAL : (int)rc_s;
  if (Rc < 128) Rc = 128;

  // zero window buffer so pad tokens are exact zeros before qkv GEMM
  hipMemsetAsync(R1, 0, (size_t)MWIN * CH * sizeof(u16), stream);

  // 1) NCHW -> NHWC (shortcut copy)
  k_nchw2nhwc<<<dim3(128, 24, NIMG), dim3(32, 8), 0, stream>>>(hidden, x_nhwc);
  // 2) LN1 -> window-partitioned xln (R1, bf16)
  k_ln<<<MREAL, 256, 0, stream>>>(x_nhwc, ln1_w, ln1_b, R1, 1);
  // 3+4) per window chunk: qkv GEMM -> R2, then attention -> R1 (overwrites
  //      this chunk's xln rows, which are dead after its qkv GEMM)
  for (int w0 = 0; w0 < NWINS; w0 += Wc) {
    int wc = NWINS - w0 < Wc ? NWINS - w0 : Wc;
    int Mc = wc * NTOK;
    k_gemm<<<dim3(18, (Mc + 127) / 128), 256, 0, stream>>>(
        R1 + (size_t)w0 * NTOK * CH, qkv_w, qkv_b, R2,
        Mc, 3 * CH, CH, 0, 0, 0);
    k_attn<<<dim3(NHEAD, wc), 256, 0, stream>>>(R2, rel_h, rel_w, R1, w0);
  }
  // 5) proj + window-unpartition residual add into x_nhwc
  k_gemm<<<dim3(6, (MWIN + 127) / 128), 256, 0, stream>>>(
      R1, proj_w, proj_b, x_nhwc, MWIN, CH, CH, 0, 2, 0);
  // 6) LN2 -> y_ln (R1 rows 0..16383)
  k_ln<<<MREAL, 256, 0, stream>>>(x_nhwc, ln2_w, ln2_b, R1, 0);
  // 7+8) per row chunk: fc1+GELU -> R2, fc2 + residual add into x_nhwc
  for (int r0 = 0; r0 < MREAL; r0 += Rc) {
    int rc = MREAL - r0 < Rc ? MREAL - r0 : Rc;
    k_gemm<<<dim3(24, (rc + 127) / 128), 256, 0, stream>>>(
        R1 + (size_t)r0 * CH, fc1_w, fc1_b, R2, rc, MLPC, CH, 1, 0, 0);
    k_gemm<<<dim3(6, (rc + 127) / 128), 256, 0, stream>>>(
        R2, fc2_w, fc2_b, x_nhwc + (size_t)r0 * CH, rc, CH, MLPC, 0, 1, 0);
  }
  // 9) NHWC -> NCHW output
  k_nhwc2nchw<<<dim3(128, 24, NIMG), dim3(32, 8), 0, stream>>>(x_nhwc, out);
}

// Round 3
// 1373.731 us; speedup vs baseline: 2.5701x; 2.5701x over previous
//
#include <hip/hip_runtime.h>
#include <cstdint>
#include <cstddef>

// Problem constants (ViTDet block, B=4, 64x64, DIM=768, 14x14 windows)
#define NIMG   4
#define GRIDSZ 64          // H = W = 64
#define CH     768
#define NHEAD  12
#define WSZ    14
#define NWINS  100         // 4 images * 5*5 windows
#define NTOK   196         // 14*14
#define MWIN   19600       // NWINS*NTOK
#define MREAL  16384       // 4*64*64
#define MLPC   3072
#define QKSCALE 0.125f

typedef unsigned short u16;
typedef __attribute__((ext_vector_type(8))) short bf16x8;
typedef __attribute__((ext_vector_type(4))) float f32x4;

__device__ __forceinline__ float b2f(u16 u) {
  uint32_t x = (uint32_t)u << 16; float f; __builtin_memcpy(&f, &x, 4); return f;
}
__device__ __forceinline__ u16 f2b(float f) {
  uint32_t x; __builtin_memcpy(&x, &f, 4);
  x += 0x7fffu + ((x >> 16) & 1u);           // round-to-nearest-even
  return (u16)(x >> 16);
}

// async global->LDS, 16B per lane; lds base must be wave-uniform
__device__ __forceinline__ void gl_lds16(const u16* g, u16* l) {
  __builtin_amdgcn_global_load_lds(
      (const __attribute__((address_space(1))) unsigned int*)g,
      (__attribute__((address_space(3))) unsigned int*)l, 16, 0, 0);
}

// ---------------------------------------------------------------------------
// Transpose NCHW -> NHWC  (f32 -> f32), 32x32 LDS tiles
// ---------------------------------------------------------------------------
__global__ __launch_bounds__(256) void k_nchw2nhwc(const float* __restrict__ in,
                                                   float* __restrict__ out) {
  __shared__ float tile[32][33];
  int b  = blockIdx.z;
  int g0 = blockIdx.x * 32;
  int c0 = blockIdx.y * 32;
  int tx = threadIdx.x, ty = threadIdx.y;  // 32 x 8
  const float* ip = in + (size_t)b * CH * 4096;
  float* op = out + (size_t)b * 4096 * CH;
#pragma unroll
  for (int k = 0; k < 32; k += 8)
    tile[ty + k][tx] = ip[(size_t)(c0 + ty + k) * 4096 + g0 + tx];
  __syncthreads();
#pragma unroll
  for (int k = 0; k < 32; k += 8)
    op[(size_t)(g0 + ty + k) * CH + c0 + tx] = tile[tx][ty + k];
}

__global__ __launch_bounds__(256) void k_nhwc2nchw(const float* __restrict__ in,
                                                   float* __restrict__ out) {
  __shared__ float tile[32][33];
  int b  = blockIdx.z;
  int g0 = blockIdx.x * 32;
  int c0 = blockIdx.y * 32;
  int tx = threadIdx.x, ty = threadIdx.y;
  const float* ip = in + (size_t)b * 4096 * CH;
  float* op = out + (size_t)b * CH * 4096;
#pragma unroll
  for (int k = 0; k < 32; k += 8)
    tile[ty + k][tx] = ip[(size_t)(g0 + ty + k) * CH + c0 + tx];
  __syncthreads();
#pragma unroll
  for (int k = 0; k < 32; k += 8)
    op[(size_t)(c0 + ty + k) * 4096 + g0 + tx] = tile[tx][ty + k];
}

// ---------------------------------------------------------------------------
// Weight convert+transpose: in f32 [K][N] -> out bf16 [N][K]
// ---------------------------------------------------------------------------
__global__ __launch_bounds__(256) void k_wt(const float* __restrict__ in,
                                            u16* __restrict__ out,
                                            int K, int N) {
  __shared__ float t[32][33];
  int n0 = blockIdx.x * 32, k0 = blockIdx.y * 32;
  int tx = threadIdx.x, ty = threadIdx.y;  // 32 x 8
#pragma unroll
  for (int k = 0; k < 32; k += 8)
    t[ty + k][tx] = in[(size_t)(k0 + ty + k) * N + n0 + tx];
  __syncthreads();
#pragma unroll
  for (int k = 0; k < 32; k += 8)
    out[(size_t)(n0 + ty + k) * K + k0 + tx] = f2b(t[tx][ty + k]);
}

// ---------------------------------------------------------------------------
// LayerNorm over 768 channels (f32 in, bf16 out). One 256-thr block per row.
// ---------------------------------------------------------------------------
__device__ __forceinline__ float block_sum(float s, float* red) {
  __syncthreads();
#pragma unroll
  for (int off = 32; off > 0; off >>= 1) s += __shfl_down(s, off, 64);
  int wid = threadIdx.x >> 6, lane = threadIdx.x & 63;
  if (lane == 0) red[wid] = s;
  __syncthreads();
  return red[0] + red[1] + red[2] + red[3];
}

__global__ __launch_bounds__(256) void k_ln(const float* __restrict__ x,
                                            const float* __restrict__ wt,
                                            const float* __restrict__ bs,
                                            u16* __restrict__ y,
                                            int window_mode) {
  __shared__ float red[4];
  int row = blockIdx.x, tid = threadIdx.x;
  const float* xp = x + (size_t)row * CH;
  float v0 = xp[tid], v1 = xp[tid + 256], v2 = xp[tid + 512];
  float mu = block_sum(v0 + v1 + v2, red) * (1.0f / 768.0f);
  float d0 = v0 - mu, d1 = v1 - mu, d2 = v2 - mu;
  float var = block_sum(d0 * d0 + d1 * d1 + d2 * d2, red) * (1.0f / 768.0f);
  float rs = rsqrtf(var + 1e-6f);
  int orow = row;
  if (window_mode) {
    int b = row >> 12, hw = row & 4095;
    int h = hw >> 6, wc = hw & 63;
    orow = (b * 25 + (h / WSZ) * 5 + (wc / WSZ)) * NTOK + (h % WSZ) * WSZ + (wc % WSZ);
  }
  u16* yp = y + (size_t)orow * CH;
  yp[tid]       = f2b(d0 * rs * wt[tid]       + bs[tid]);
  yp[tid + 256] = f2b(d1 * rs * wt[tid + 256] + bs[tid + 256]);
  yp[tid + 512] = f2b(d2 * rs * wt[tid + 512] + bs[tid + 512]);
}

// ---------------------------------------------------------------------------
// bf16 MFMA GEMM: C = act(A[MxK] @ BT[NxK]^T + bias), fp32 accumulate.
// 128x128 tile, BK=32, 256 thr (4 waves, each 64x64 via 4x4 mfma 16x16x32).
// global_load_lds width-16 staging (m97 structure). N%128==0, K%32==0.
// mode 0: C bf16 store   mode 1: C f32 +=   mode 2: window-unpartition f32 +=
// act 1: exact GELU
// ---------------------------------------------------------------------------
__global__ __launch_bounds__(256) void k_gemm_mfma(const u16* __restrict__ A,
                                                   const u16* __restrict__ BT,
                                                   const float* __restrict__ bias,
                                                   void* __restrict__ Cv,
                                                   int M, int N, int K,
                                                   int act, int mode, int row0) {
  __shared__ u16 As[128 * 32];
  __shared__ u16 Bs[128 * 32];
  int tid  = threadIdx.x;
  int lane = tid & 63, wave = tid >> 6;
  int bn = blockIdx.x, bm = blockIdx.y;
  int wm = (wave & 1) * 64, wn = (wave >> 1) * 64;
  int mrow = lane & 15, quad = lane >> 4;

  f32x4 acc[4][4];
#pragma unroll
  for (int i = 0; i < 4; i++)
#pragma unroll
    for (int j = 0; j < 4; j++) acc[i][j] = (f32x4){0.f, 0.f, 0.f, 0.f};

  const u16* Atile = A + (size_t)bm * 128 * K;
  const u16* Btile = BT + (size_t)bn * 128 * K;

  // staging: tile is 128 rows x 64B; chunk c (0..511) = row c>>2, byte (c&3)*16
  int c0 = wave * 64 + lane;
  int c1 = c0 + 256;
  int ar0 = c0 >> 2, ao0 = (c0 & 3) * 8;   // element offsets
  int ar1 = c1 >> 2, ao1 = (c1 & 3) * 8;
  u16* lA0 = As + (size_t)(wave * 64) * 8;        // wave-uniform LDS bases
  u16* lA1 = As + (size_t)(256 + wave * 64) * 8;
  u16* lB0 = Bs + (size_t)(wave * 64) * 8;
  u16* lB1 = Bs + (size_t)(256 + wave * 64) * 8;

  for (int k0 = 0; k0 < K; k0 += 32) {
    __syncthreads();
    gl_lds16(Atile + (size_t)ar0 * K + k0 + ao0, lA0);
    gl_lds16(Atile + (size_t)ar1 * K + k0 + ao1, lA1);
    gl_lds16(Btile + (size_t)ar0 * K + k0 + ao0, lB0);
    gl_lds16(Btile + (size_t)ar1 * K + k0 + ao1, lB1);
    __syncthreads();
    bf16x8 af[4], bfv[4];
#pragma unroll
    for (int mi = 0; mi < 4; mi++)
      af[mi] = *(const bf16x8*)&As[(size_t)(wm + mi * 16 + mrow) * 32 + quad * 8];
#pragma unroll
    for (int ni = 0; ni < 4; ni++)
      bfv[ni] = *(const bf16x8*)&Bs[(size_t)(wn + ni * 16 + mrow) * 32 + quad * 8];
#pragma unroll
    for (int mi = 0; mi < 4; mi++)
#pragma unroll
      for (int ni = 0; ni < 4; ni++)
        acc[mi][ni] = __builtin_amdgcn_mfma_f32_16x16x32_bf16(
            af[mi], bfv[ni], acc[mi][ni], 0, 0, 0);
  }

  // epilogue: C/D layout col = lane&15, row = quad*4 + reg
#pragma unroll
  for (int mi = 0; mi < 4; mi++) {
#pragma unroll
    for (int r = 0; r < 4; r++) {
      int row = bm * 128 + wm + mi * 16 + quad * 4 + r;
      if (row >= M) continue;
      size_t gbase = 0;
      bool valid = true;
      if (mode == 2) {  // window slot -> image token (skip pad)
        int rowa = row + row0;
        int widx = rowa / NTOK, tt = rowa % NTOK;
        int b = widx / 25, wq = widx % 25;
        int h = (wq / 5) * WSZ + tt / WSZ;
        int w = (wq % 5) * WSZ + tt % WSZ;
        valid = (h < GRIDSZ) && (w < GRIDSZ);
        gbase = valid ? ((size_t)((b * GRIDSZ + h) * GRIDSZ + w)) * CH : 0;
      }
#pragma unroll
      for (int ni = 0; ni < 4; ni++) {
        int col = bn * 128 + wn + ni * 16 + mrow;
        float v = acc[mi][ni][r] + bias[col];
        if (act == 1) v = 0.5f * v * (1.0f + erff(v * 0.70710678118654752440f));
        if (mode == 0)      ((u16*)Cv)[(size_t)row * N + col] = f2b(v);
        else if (mode == 1) ((float*)Cv)[(size_t)row * N + col] += v;
        else if (valid)     ((float*)Cv)[gbase + col] += v;
      }
    }
  }
}

// ---------------------------------------------------------------------------
// Windowed attention: one block per (head, local window). qkv bf16 chunk-local;
// output bf16 at absolute window win0+blockIdx.y. Rel-pos from UNSCALED q.
// ---------------------------------------------------------------------------
#define KTILE 49
#define RSTR  15
__global__ __launch_bounds__(256) void k_attn(const u16* __restrict__ qkv,
                                              const float* __restrict__ rel_h,
                                              const float* __restrict__ rel_w,
                                              u16* __restrict__ out, int win0) {
  __shared__ float Ks[KTILE * 64];
  __shared__ float Vs[KTILE * 64];
  __shared__ float rhs[NTOK * RSTR];
  __shared__ float rws[NTOK * RSTR];
  int head = blockIdx.x;
  int wloc = blockIdx.y;
  int tid  = threadIdx.x;
  size_t base = (size_t)wloc * NTOK * (3 * CH);
  int hoff = head * 64;

  float q[64];
  float o[64];
  float l = 0.0f;
  if (tid < NTOK) {
    const u16* qp = qkv + base + (size_t)tid * (3 * CH) + hoff;
#pragma unroll
    for (int d = 0; d < 64; d += 4) {
      ushort4 u4 = *(const ushort4*)(qp + d);
      q[d] = b2f(u4.x); q[d + 1] = b2f(u4.y); q[d + 2] = b2f(u4.z); q[d + 3] = b2f(u4.w);
    }
#pragma unroll
    for (int d = 0; d < 64; d++) o[d] = 0.0f;
    int hq = tid / WSZ, wq = tid % WSZ;
    for (int kk = 0; kk < WSZ; kk++) {
      const float* rh = rel_h + (size_t)(hq - kk + WSZ - 1) * 64;
      const float* rw = rel_w + (size_t)(wq - kk + WSZ - 1) * 64;
      float sh = 0.0f, sw = 0.0f;
#pragma unroll
      for (int d = 0; d < 64; d++) { sh += q[d] * rh[d]; sw += q[d] * rw[d]; }
      rhs[tid * RSTR + kk] = sh;
      rws[tid * RSTR + kk] = sw;
    }
  }

  for (int t = 0; t < 4; t++) {
    __syncthreads();
    for (int idx = tid; idx < KTILE * 64; idx += 256) {
      int j = idx >> 6, d = idx & 63;
      size_t src = base + (size_t)(t * KTILE + j) * (3 * CH) + hoff + d;
      Ks[idx] = b2f(qkv[src + CH]);
      Vs[idx] = b2f(qkv[src + 2 * CH]);
    }
    __syncthreads();
    if (tid < NTOK) {
      for (int jj = 0; jj < KTILE; jj++) {
        int j = t * KTILE + jj;
        int jh = j / WSZ, jw = j % WSZ;
        const float* kp = &Ks[jj * 64];
        float s = 0.0f;
#pragma unroll
        for (int d = 0; d < 64; d++) s += q[d] * kp[d];
        s = s * QKSCALE + rhs[tid * RSTR + jh] + rws[tid * RSTR + jw];
        float p = __expf(s);
        l += p;
        const float* vp = &Vs[jj * 64];
#pragma unroll
        for (int d = 0; d < 64; d++) o[d] += p * vp[d];
      }
    }
  }

  if (tid < NTOK) {
    float inv = 1.0f / l;
    u16* op = out + ((size_t)(win0 + wloc) * NTOK + tid) * CH + hoff;
#pragma unroll
    for (int d = 0; d < 64; d++) op[d] = f2b(o[d] * inv);
  }
}

// ---------------------------------------------------------------------------
extern "C" void kernel_launch(void* const* d_in, const int* in_sizes, int n_in,
                              void* d_out, int out_size, void* d_ws, size_t ws_size,
                              hipStream_t stream) {
  const float* hidden = (const float*)d_in[0];
  const float* ln1_w  = (const float*)d_in[1];
  const float* ln1_b  = (const float*)d_in[2];
  const float* qkv_w  = (const float*)d_in[3];
  const float* qkv_b  = (const float*)d_in[4];
  const float* proj_w = (const float*)d_in[5];
  const float* proj_b = (const float*)d_in[6];
  const float* rel_h  = (const float*)d_in[7];
  const float* rel_w  = (const float*)d_in[8];
  const float* ln2_w  = (const float*)d_in[9];
  const float* ln2_b  = (const float*)d_in[10];
  const float* fc1_w  = (const float*)d_in[11];
  const float* fc1_b  = (const float*)d_in[12];
  const float* fc2_w  = (const float*)d_in[13];
  const float* fc2_b  = (const float*)d_in[14];
  float* out = (float*)d_out;

  // Workspace layout (bytes):
  //   x_nhwc f32 : 50,331,648                  (residual accumulator)
  //   R1 bf16    : 30,105,600  (19600x768: xln -> attn_out -> y_ln)
  //   WT bf16    : 14,155,776  (qkv_wT | proj_wT | fc1_wT | fc2_wT)
  //   R2 bf16    : remainder   (qkv chunks / mlp-hidden chunks)
  char* ws = (char*)d_ws;
  float* x_nhwc = (float*)ws;
  u16*   R1     = (u16*)(ws + 50331648);
  u16*   qkvT   = (u16*)(ws + 80437248);
  u16*   projT  = qkvT + (size_t)2304 * 768;
  u16*   fc1T   = projT + (size_t)768 * 768;
  u16*   fc2T   = fc1T + (size_t)3072 * 768;
  u16*   R2     = fc2T + (size_t)768 * 3072;
  size_t used   = (size_t)80437248 + 14155776;
  size_t r2e    = ws_size > used ? (ws_size - used) >> 1 : 0;  // bf16 elems

  size_t wc_s = r2e / ((size_t)NTOK * 3 * CH);
  int Wc = wc_s >= NWINS ? NWINS : (int)wc_s;
  if (Wc < 1) Wc = 1;
  size_t rc_s = (r2e / MLPC / 128) * 128;
  int Rc = rc_s >= MREAL ? MREAL : (int)rc_s;
  if (Rc < 128) Rc = 128;

  // 0) weight convert + transpose (f32 [K][N] -> bf16 [N][K])
  k_wt<<<dim3(72, 24), dim3(32, 8), 0, stream>>>(qkv_w, qkvT, CH, 3 * CH);
  k_wt<<<dim3(24, 24), dim3(32, 8), 0, stream>>>(proj_w, projT, CH, CH);
  k_wt<<<dim3(96, 24), dim3(32, 8), 0, stream>>>(fc1_w, fc1T, CH, MLPC);
  k_wt<<<dim3(24, 96), dim3(32, 8), 0, stream>>>(fc2_w, fc2T, MLPC, CH);

  // zero window buffer so pad tokens are exact zeros before qkv GEMM
  hipMemsetAsync(R1, 0, (size_t)MWIN * CH * sizeof(u16), stream);

  // 1) NCHW -> NHWC (shortcut copy)
  k_nchw2nhwc<<<dim3(128, 24, NIMG), dim3(32, 8), 0, stream>>>(hidden, x_nhwc);
  // 2) LN1 -> window-partitioned xln (R1, bf16)
  k_ln<<<MREAL, 256, 0, stream>>>(x_nhwc, ln1_w, ln1_b, R1, 1);
  // 3+4) per window chunk: qkv GEMM -> R2, then attention -> R1
  for (int w0 = 0; w0 < NWINS; w0 += Wc) {
    int wc = NWINS - w0 < Wc ? NWINS - w0 : Wc;
    int Mc = wc * NTOK;
    k_gemm_mfma<<<dim3(18, (Mc + 127) / 128), 256, 0, stream>>>(
        R1 + (size_t)w0 * NTOK * CH, qkvT, qkv_b, R2,
        Mc, 3 * CH, CH, 0, 0, 0);
    k_attn<<<dim3(NHEAD, wc), 256, 0, stream>>>(R2, rel_h, rel_w, R1, w0);
  }
  // 5) proj + window-unpartition residual add into x_nhwc
  k_gemm_mfma<<<dim3(6, (MWIN + 127) / 128), 256, 0, stream>>>(
      R1, projT, proj_b, x_nhwc, MWIN, CH, CH, 0, 2, 0);
  // 6) LN2 -> y_ln (R1 rows 0..16383)
  k_ln<<<MREAL, 256, 0, stream>>>(x_nhwc, ln2_w, ln2_b, R1, 0);
  // 7+8) per row chunk: fc1+GELU -> R2, fc2 + residual add into x_nhwc
  for (int r0 = 0; r0 < MREAL; r0 += Rc) {
    int rc = MREAL - r0 < Rc ? MREAL - r0 : Rc;
    k_gemm_mfma<<<dim3(24, (rc + 127) / 128), 256, 0, stream>>>(
        R1 + (size_t)r0 * CH, fc1T, fc1_b, R2, rc, MLPC, CH, 1, 0, 0);
    k_gemm_mfma<<<dim3(6, (rc + 127) / 128), 256, 0, stream>>>(
        R2, fc2T, fc2_b, x_nhwc + (size_t)r0 * CH, rc, CH, MLPC, 0, 1, 0);
  }
  // 9) NHWC -> NCHW output
  k_nhwc2nchw<<<dim3(128, 24, NIMG), dim3(32, 8), 0, stream>>>(x_nhwc, out);
}

// Round 4
// 962.368 us; speedup vs baseline: 3.6687x; 1.4274x over previous
//
#include <hip/hip_runtime.h>
#include <cstdint>
#include <cstddef>

// Problem constants (ViTDet block, B=4, 64x64, DIM=768, 14x14 windows)
#define NIMG   4
#define GRIDSZ 64          // H = W = 64
#define CH     768
#define NHEAD  12
#define WSZ    14
#define NWINS  100         // 4 images * 5*5 windows
#define NTOK   196         // 14*14
#define MWIN   19600       // NWINS*NTOK
#define MREAL  16384       // 4*64*64
#define MLPC   3072
#define QKSCALE 0.125f

#define KSTR 72            // Ks LDS row stride (u16): 144B rows -> 2-way banks
#define VSTR 216           // Vt row stride (u16): 432B rows -> 2-way banks
#define PSTR 40            // P slice row stride (u16): 80B rows -> 2-way banks

typedef unsigned short u16;
typedef __attribute__((ext_vector_type(8))) short bf16x8;
typedef __attribute__((ext_vector_type(4))) float f32x4;

__device__ __forceinline__ float b2f(u16 u) {
  uint32_t x = (uint32_t)u << 16; float f; __builtin_memcpy(&f, &x, 4); return f;
}
__device__ __forceinline__ u16 f2b(float f) {
  uint32_t x; __builtin_memcpy(&x, &f, 4);
  x += 0x7fffu + ((x >> 16) & 1u);           // round-to-nearest-even
  return (u16)(x >> 16);
}

// async global->LDS, 16B per lane; lds base must be wave-uniform
__device__ __forceinline__ void gl_lds16(const u16* g, u16* l) {
  __builtin_amdgcn_global_load_lds(
      (const __attribute__((address_space(1))) unsigned int*)g,
      (__attribute__((address_space(3))) unsigned int*)l, 16, 0, 0);
}

// ---------------------------------------------------------------------------
// Transpose NCHW -> NHWC  (f32 -> f32), 32x32 LDS tiles
// ---------------------------------------------------------------------------
__global__ __launch_bounds__(256) void k_nchw2nhwc(const float* __restrict__ in,
                                                   float* __restrict__ out) {
  __shared__ float tile[32][33];
  int b  = blockIdx.z;
  int g0 = blockIdx.x * 32;
  int c0 = blockIdx.y * 32;
  int tx = threadIdx.x, ty = threadIdx.y;  // 32 x 8
  const float* ip = in + (size_t)b * CH * 4096;
  float* op = out + (size_t)b * 4096 * CH;
#pragma unroll
  for (int k = 0; k < 32; k += 8)
    tile[ty + k][tx] = ip[(size_t)(c0 + ty + k) * 4096 + g0 + tx];
  __syncthreads();
#pragma unroll
  for (int k = 0; k < 32; k += 8)
    op[(size_t)(g0 + ty + k) * CH + c0 + tx] = tile[tx][ty + k];
}

__global__ __launch_bounds__(256) void k_nhwc2nchw(const float* __restrict__ in,
                                                   float* __restrict__ out) {
  __shared__ float tile[32][33];
  int b  = blockIdx.z;
  int g0 = blockIdx.x * 32;
  int c0 = blockIdx.y * 32;
  int tx = threadIdx.x, ty = threadIdx.y;
  const float* ip = in + (size_t)b * 4096 * CH;
  float* op = out + (size_t)b * CH * 4096;
#pragma unroll
  for (int k = 0; k < 32; k += 8)
    tile[ty + k][tx] = ip[(size_t)(g0 + ty + k) * CH + c0 + tx];
  __syncthreads();
#pragma unroll
  for (int k = 0; k < 32; k += 8)
    op[(size_t)(c0 + ty + k) * 4096 + g0 + tx] = tile[tx][ty + k];
}

// ---------------------------------------------------------------------------
// Weight convert+transpose: in f32 [K][N] -> out bf16 [N][K]
// ---------------------------------------------------------------------------
__global__ __launch_bounds__(256) void k_wt(const float* __restrict__ in,
                                            u16* __restrict__ out,
                                            int K, int N) {
  __shared__ float t[32][33];
  int n0 = blockIdx.x * 32, k0 = blockIdx.y * 32;
  int tx = threadIdx.x, ty = threadIdx.y;  // 32 x 8
#pragma unroll
  for (int k = 0; k < 32; k += 8)
    t[ty + k][tx] = in[(size_t)(k0 + ty + k) * N + n0 + tx];
  __syncthreads();
#pragma unroll
  for (int k = 0; k < 32; k += 8)
    out[(size_t)(n0 + ty + k) * K + k0 + tx] = f2b(t[tx][ty + k]);
}

// ---------------------------------------------------------------------------
// LayerNorm over 768 channels (f32 in, bf16 out). One 256-thr block per row.
// ---------------------------------------------------------------------------
__device__ __forceinline__ float block_sum(float s, float* red) {
  __syncthreads();
#pragma unroll
  for (int off = 32; off > 0; off >>= 1) s += __shfl_down(s, off, 64);
  int wid = threadIdx.x >> 6, lane = threadIdx.x & 63;
  if (lane == 0) red[wid] = s;
  __syncthreads();
  return red[0] + red[1] + red[2] + red[3];
}

__global__ __launch_bounds__(256) void k_ln(const float* __restrict__ x,
                                            const float* __restrict__ wt,
                                            const float* __restrict__ bs,
                                            u16* __restrict__ y,
                                            int window_mode) {
  __shared__ float red[4];
  int row = blockIdx.x, tid = threadIdx.x;
  const float* xp = x + (size_t)row * CH;
  float v0 = xp[tid], v1 = xp[tid + 256], v2 = xp[tid + 512];
  float mu = block_sum(v0 + v1 + v2, red) * (1.0f / 768.0f);
  float d0 = v0 - mu, d1 = v1 - mu, d2 = v2 - mu;
  float var = block_sum(d0 * d0 + d1 * d1 + d2 * d2, red) * (1.0f / 768.0f);
  float rs = rsqrtf(var + 1e-6f);
  int orow = row;
  if (window_mode) {
    int b = row >> 12, hw = row & 4095;
    int h = hw >> 6, wc = hw & 63;
    orow = (b * 25 + (h / WSZ) * 5 + (wc / WSZ)) * NTOK + (h % WSZ) * WSZ + (wc % WSZ);
  }
  u16* yp = y + (size_t)orow * CH;
  yp[tid]       = f2b(d0 * rs * wt[tid]       + bs[tid]);
  yp[tid + 256] = f2b(d1 * rs * wt[tid + 256] + bs[tid + 256]);
  yp[tid + 512] = f2b(d2 * rs * wt[tid + 512] + bs[tid + 512]);
}

// ---------------------------------------------------------------------------
// bf16 MFMA GEMM: C = act(A[MxK] @ BT[NxK]^T + bias), fp32 accumulate.
// 128x128 tile, BK=32, 256 thr (4 waves, each 64x64 via 4x4 mfma 16x16x32).
// mode 0: C bf16 store   mode 1: C f32 +=   mode 2: window-unpartition f32 +=
// mode 3: qkv split: cols<1536 -> C bf16; V cols -> Vt[(wloc*12+h)*64+d][tok]
// act 1: exact GELU
// ---------------------------------------------------------------------------
__global__ __launch_bounds__(256) void k_gemm_mfma(const u16* __restrict__ A,
                                                   const u16* __restrict__ BT,
                                                   const float* __restrict__ bias,
                                                   void* __restrict__ Cv,
                                                   u16* __restrict__ Vt,
                                                   int M, int N, int K,
                                                   int act, int mode, int row0) {
  __shared__ u16 As[128 * 32];
  __shared__ u16 Bs[128 * 32];
  int tid  = threadIdx.x;
  int lane = tid & 63, wave = tid >> 6;
  int bn = blockIdx.x, bm = blockIdx.y;
  int wm = (wave & 1) * 64, wn = (wave >> 1) * 64;
  int mrow = lane & 15, quad = lane >> 4;

  f32x4 acc[4][4];
#pragma unroll
  for (int i = 0; i < 4; i++)
#pragma unroll
    for (int j = 0; j < 4; j++) acc[i][j] = (f32x4){0.f, 0.f, 0.f, 0.f};

  const u16* Atile = A + (size_t)bm * 128 * K;
  const u16* Btile = BT + (size_t)bn * 128 * K;

  int c0 = wave * 64 + lane;
  int c1 = c0 + 256;
  int ar0 = c0 >> 2, ao0 = (c0 & 3) * 8;
  int ar1 = c1 >> 2, ao1 = (c1 & 3) * 8;
  u16* lA0 = As + (size_t)(wave * 64) * 8;
  u16* lA1 = As + (size_t)(256 + wave * 64) * 8;
  u16* lB0 = Bs + (size_t)(wave * 64) * 8;
  u16* lB1 = Bs + (size_t)(256 + wave * 64) * 8;

  for (int k0 = 0; k0 < K; k0 += 32) {
    __syncthreads();
    gl_lds16(Atile + (size_t)ar0 * K + k0 + ao0, lA0);
    gl_lds16(Atile + (size_t)ar1 * K + k0 + ao1, lA1);
    gl_lds16(Btile + (size_t)ar0 * K + k0 + ao0, lB0);
    gl_lds16(Btile + (size_t)ar1 * K + k0 + ao1, lB1);
    __syncthreads();
    bf16x8 af[4], bfv[4];
#pragma unroll
    for (int mi = 0; mi < 4; mi++)
      af[mi] = *(const bf16x8*)&As[(size_t)(wm + mi * 16 + mrow) * 32 + quad * 8];
#pragma unroll
    for (int ni = 0; ni < 4; ni++)
      bfv[ni] = *(const bf16x8*)&Bs[(size_t)(wn + ni * 16 + mrow) * 32 + quad * 8];
#pragma unroll
    for (int mi = 0; mi < 4; mi++)
#pragma unroll
      for (int ni = 0; ni < 4; ni++)
        acc[mi][ni] = __builtin_amdgcn_mfma_f32_16x16x32_bf16(
            af[mi], bfv[ni], acc[mi][ni], 0, 0, 0);
  }

  // epilogue: C/D layout col = lane&15, row = quad*4 + reg
#pragma unroll
  for (int mi = 0; mi < 4; mi++) {
#pragma unroll
    for (int r = 0; r < 4; r++) {
      int row = bm * 128 + wm + mi * 16 + quad * 4 + r;
      if (row >= M) continue;
      size_t gbase = 0;
      bool valid = true;
      if (mode == 2) {  // window slot -> image token (skip pad)
        int rowa = row + row0;
        int widx = rowa / NTOK, tt = rowa % NTOK;
        int b = widx / 25, wq = widx % 25;
        int h = (wq / 5) * WSZ + tt / WSZ;
        int w = (wq % 5) * WSZ + tt % WSZ;
        valid = (h < GRIDSZ) && (w < GRIDSZ);
        gbase = valid ? ((size_t)((b * GRIDSZ + h) * GRIDSZ + w)) * CH : 0;
      }
      int wloc = 0, tok = 0;
      if (mode == 3) { wloc = row / NTOK; tok = row - wloc * NTOK; }
#pragma unroll
      for (int ni = 0; ni < 4; ni++) {
        int col = bn * 128 + wn + ni * 16 + mrow;
        float v = acc[mi][ni][r] + bias[col];
        if (act == 1) v = 0.5f * v * (1.0f + erff(v * 0.70710678118654752440f));
        if (mode == 0)      ((u16*)Cv)[(size_t)row * N + col] = f2b(v);
        else if (mode == 1) ((float*)Cv)[(size_t)row * N + col] += v;
        else if (mode == 2) { if (valid) ((float*)Cv)[gbase + col] += v; }
        else {  // mode 3
          if (col < 1536) ((u16*)Cv)[(size_t)row * N + col] = f2b(v);
          else {
            int vv = col - 1536, hd = vv >> 6, d = vv & 63;
            Vt[((size_t)(wloc * NHEAD + hd) * 64 + d) * VSTR + tok] = f2b(v);
          }
        }
      }
    }
  }
}

// ---------------------------------------------------------------------------
// Rel-pos bias tables from UNSCALED q: rhg/rwg[(wloc*12+head)*196+tok][16]
// (kk 0..13 valid). One thread per (row, head).
// ---------------------------------------------------------------------------
__global__ __launch_bounds__(256) void k_relbias(const u16* __restrict__ qkv,
                                                 const float* __restrict__ rel_h,
                                                 const float* __restrict__ rel_w,
                                                 u16* __restrict__ rhg,
                                                 u16* __restrict__ rwg,
                                                 int nrows) {
  int idx = blockIdx.x * 256 + threadIdx.x;
  if (idx >= nrows * NHEAD) return;
  int head = idx % NHEAD, row = idx / NHEAD;
  int wloc = row / NTOK, tok = row - wloc * NTOK;
  const u16* qp = qkv + (size_t)row * (3 * CH) + head * 64;
  float q[64];
#pragma unroll
  for (int d = 0; d < 64; d += 4) {
    ushort4 u4 = *(const ushort4*)(qp + d);
    q[d] = b2f(u4.x); q[d + 1] = b2f(u4.y); q[d + 2] = b2f(u4.z); q[d + 3] = b2f(u4.w);
  }
  int hq = tok / WSZ, wq = tok % WSZ;
  size_t obase = ((size_t)(wloc * NHEAD + head) * NTOK + tok) * 16;
  for (int kk = 0; kk < WSZ; kk++) {
    const float* rh = rel_h + (size_t)(hq - kk + WSZ - 1) * 64;
    const float* rw = rel_w + (size_t)(wq - kk + WSZ - 1) * 64;
    float sh = 0.0f, sw = 0.0f;
#pragma unroll
    for (int d = 0; d < 64; d++) { sh += q[d] * rh[d]; sw += q[d] * rw[d]; }
    rhg[obase + kk] = f2b(sh);
    rwg[obase + kk] = f2b(sw);
  }
}

// ---------------------------------------------------------------------------
// MFMA windowed attention. One block per (head, local window), 4 waves.
// Ks: [196][KSTR] row-major bf16.  Vs: V^T [64][VSTR] bf16 (from global Vt).
// Wave handles Q row-tiles {w, w+4, w+8, (w==0:12)}. S = Q K^T via mfma;
// exp-sum softmax (no max-sub; scores bounded); P -> per-wave LDS slice ->
// A-frag; O = P V via mfma with V^T B-frags. Cols>=196 masked to p=0.
// ---------------------------------------------------------------------------
__global__ __launch_bounds__(256) void k_attn_mfma(const u16* __restrict__ qkv,
                                                   const u16* __restrict__ Vt,
                                                   const u16* __restrict__ rhg,
                                                   const u16* __restrict__ rwg,
                                                   u16* __restrict__ out,
                                                   int win0) {
  __shared__ u16 Ks[NTOK * KSTR];        // 28224 B
  __shared__ u16 Vs[64 * VSTR];          // 27648 B
  __shared__ u16 Ps[4][16 * PSTR];       // 5120 B   (total 60992 B)
  int head = blockIdx.x, wloc = blockIdx.y;
  int tid = threadIdx.x, lane = tid & 63, wave = tid >> 6;
  int l15 = lane & 15, quad = lane >> 4;
  const u16* qbase = qkv + (size_t)wloc * NTOK * (3 * CH) + head * 64;

  // stage K rows (196 x 64) -> Ks stride 72
  for (int c = tid; c < NTOK * 8; c += 256) {
    int tok = c >> 3, part = c & 7;
    uint4 v = *(const uint4*)(qbase + (size_t)tok * (3 * CH) + CH + part * 8);
    *(uint4*)&Ks[tok * KSTR + part * 8] = v;
  }
  // stage V^T (64 x VSTR, layout-identical in global) via global_load_lds
  const u16* vb = Vt + (size_t)(wloc * NHEAD + head) * 64 * VSTR;
#pragma unroll
  for (int it = 0; it < 7; ++it) {
    int c = it * 256 + tid;
    if (c < 64 * VSTR / 8) gl_lds16(vb + (size_t)c * 8, Vs + ((size_t)it * 256 + wave * 64) * 8);
  }
  __syncthreads();

  const u16* rhp = rhg + ((size_t)(wloc * NHEAD + head) * NTOK) * 16;
  const u16* rwp = rwg + ((size_t)(wloc * NHEAD + head) * NTOK) * 16;
  int winabs = win0 + wloc;

  for (int t16 = wave; t16 < 13; t16 += 4) {
    // Q A-frags (row = l15, k = quad*8..)
    int qtok = t16 * 16 + l15; if (qtok > NTOK - 1) qtok = NTOK - 1;
    bf16x8 aq0 = *(const bf16x8*)(qbase + (size_t)qtok * (3 * CH) + quad * 8);
    bf16x8 aq1 = *(const bf16x8*)(qbase + (size_t)qtok * (3 * CH) + 32 + quad * 8);

    f32x4 s[13];
#pragma unroll
    for (int ct = 0; ct < 13; ct++) s[ct] = (f32x4){0.f, 0.f, 0.f, 0.f};
#pragma unroll
    for (int ct = 0; ct < 13; ct++) {
      int ktok = ct * 16 + l15; if (ktok > NTOK - 1) ktok = NTOK - 1;
      bf16x8 bk0 = *(const bf16x8*)&Ks[ktok * KSTR + quad * 8];
      bf16x8 bk1 = *(const bf16x8*)&Ks[ktok * KSTR + 32 + quad * 8];
      s[ct] = __builtin_amdgcn_mfma_f32_16x16x32_bf16(aq0, bk0, s[ct], 0, 0, 0);
      s[ct] = __builtin_amdgcn_mfma_f32_16x16x32_bf16(aq1, bk1, s[ct], 0, 0, 0);
    }

    f32x4 o[4];
#pragma unroll
    for (int ni = 0; ni < 4; ni++) o[ni] = (f32x4){0.f, 0.f, 0.f, 0.f};
    float lsum[4] = {0.f, 0.f, 0.f, 0.f};
    int row0t = t16 * 16 + quad * 4;

#pragma unroll
    for (int cc = 0; cc < 7; ++cc) {
#pragma unroll
      for (int half = 0; half < 2; ++half) {
        int ct = cc * 2 + half;
        if (ct < 13) {
          int col = ct * 16 + l15;
          int jh = col / WSZ, jw = col - jh * WSZ;
          bool colok = col < NTOK;
#pragma unroll
          for (int r = 0; r < 4; r++) {
            int rowt = row0t + r; int rowc = rowt > NTOK - 1 ? NTOK - 1 : rowt;
            float bias = b2f(rhp[rowc * 16 + jh]) + b2f(rwp[rowc * 16 + jw]);
            float sv = s[ct][r] * QKSCALE + bias;
            float p = colok ? __expf(sv) : 0.f;
            lsum[r] += p;
            Ps[wave][(quad * 4 + r) * PSTR + half * 16 + l15] = f2b(p);
          }
        } else {
#pragma unroll
          for (int r = 0; r < 4; r++)
            Ps[wave][(quad * 4 + r) * PSTR + half * 16 + l15] = 0;
        }
      }
      // wave-local LDS round-trip: P C-layout -> A-frag layout
      bf16x8 pa = *(const bf16x8*)&Ps[wave][l15 * PSTR + quad * 8];
#pragma unroll
      for (int ni = 0; ni < 4; ni++) {
        bf16x8 bv = *(const bf16x8*)&Vs[(ni * 16 + l15) * VSTR + cc * 32 + quad * 8];
        o[ni] = __builtin_amdgcn_mfma_f32_16x16x32_bf16(pa, bv, o[ni], 0, 0, 0);
      }
    }

    // row-sum reduce across the 16 lanes holding each row's columns
#pragma unroll
    for (int r = 0; r < 4; r++) {
#pragma unroll
      for (int m = 1; m < 16; m <<= 1) lsum[r] += __shfl_xor(lsum[r], m, 64);
    }

#pragma unroll
    for (int r = 0; r < 4; r++) {
      int rowt = row0t + r;
      if (rowt < NTOK) {
        float inv = 1.0f / lsum[r];
        u16* op = out + ((size_t)winabs * NTOK + rowt) * CH + head * 64;
#pragma unroll
        for (int ni = 0; ni < 4; ni++) op[ni * 16 + l15] = f2b(o[ni][r] * inv);
      }
    }
  }
}

// ---------------------------------------------------------------------------
extern "C" void kernel_launch(void* const* d_in, const int* in_sizes, int n_in,
                              void* d_out, int out_size, void* d_ws, size_t ws_size,
                              hipStream_t stream) {
  const float* hidden = (const float*)d_in[0];
  const float* ln1_w  = (const float*)d_in[1];
  const float* ln1_b  = (const float*)d_in[2];
  const float* qkv_w  = (const float*)d_in[3];
  const float* qkv_b  = (const float*)d_in[4];
  const float* proj_w = (const float*)d_in[5];
  const float* proj_b = (const float*)d_in[6];
  const float* rel_h  = (const float*)d_in[7];
  const float* rel_w  = (const float*)d_in[8];
  const float* ln2_w  = (const float*)d_in[9];
  const float* ln2_b  = (const float*)d_in[10];
  const float* fc1_w  = (const float*)d_in[11];
  const float* fc1_b  = (const float*)d_in[12];
  const float* fc2_w  = (const float*)d_in[13];
  const float* fc2_b  = (const float*)d_in[14];
  float* out = (float*)d_out;

  // Workspace layout (bytes):
  //   x_nhwc f32 : 50,331,648   (residual accumulator)
  //   R1 bf16    : 30,105,600   (19600x768: xln -> attn_out -> y_ln)
  //   WT bf16    : 14,155,776   (qkv_wT | proj_wT | fc1_wT | fc2_wT)
  //   R2 bf16    : remainder    (per-chunk: qkv | Vt | rhg | rwg ; or mlp-h)
  char* ws = (char*)d_ws;
  float* x_nhwc = (float*)ws;
  u16*   R1     = (u16*)(ws + 50331648);
  u16*   qkvT   = (u16*)(ws + 80437248);
  u16*   projT  = qkvT + (size_t)2304 * 768;
  u16*   fc1T   = projT + (size_t)768 * 768;
  u16*   fc2T   = fc1T + (size_t)3072 * 768;
  u16*   R2     = fc2T + (size_t)768 * 3072;
  size_t used   = (size_t)80437248 + 14155776;
  size_t r2e    = ws_size > used ? (ws_size - used) >> 1 : 0;  // bf16 elems

  // per-window footprint in R2: qkv rows + Vt + rhg + rwg
  const size_t PW_QKV = (size_t)NTOK * 3 * CH;            // 451584
  const size_t PW_VT  = (size_t)NHEAD * 64 * VSTR;        // 165888
  const size_t PW_RB  = (size_t)NHEAD * NTOK * 16;        // 37632 (x2 tables)
  const size_t perwin = PW_QKV + PW_VT + 2 * PW_RB;       // 692736 elems
  size_t wc_s = r2e / perwin;
  int Wc = wc_s >= NWINS ? NWINS : (int)wc_s;
  if (Wc < 1) Wc = 1;
  size_t rc_s = (r2e / MLPC / 128) * 128;
  int Rc = rc_s >= MREAL ? MREAL : (int)rc_s;
  if (Rc < 128) Rc = 128;

  u16* Vt  = R2 + (size_t)Wc * PW_QKV;
  u16* rhg = Vt + (size_t)Wc * PW_VT;
  u16* rwg = rhg + (size_t)Wc * PW_RB;

  // 0) weight convert + transpose (f32 [K][N] -> bf16 [N][K])
  k_wt<<<dim3(72, 24), dim3(32, 8), 0, stream>>>(qkv_w, qkvT, CH, 3 * CH);
  k_wt<<<dim3(24, 24), dim3(32, 8), 0, stream>>>(proj_w, projT, CH, CH);
  k_wt<<<dim3(96, 24), dim3(32, 8), 0, stream>>>(fc1_w, fc1T, CH, MLPC);
  k_wt<<<dim3(24, 96), dim3(32, 8), 0, stream>>>(fc2_w, fc2T, MLPC, CH);

  // zero window buffer so pad tokens are exact zeros before qkv GEMM
  hipMemsetAsync(R1, 0, (size_t)MWIN * CH * sizeof(u16), stream);

  // 1) NCHW -> NHWC (shortcut copy)
  k_nchw2nhwc<<<dim3(128, 24, NIMG), dim3(32, 8), 0, stream>>>(hidden, x_nhwc);
  // 2) LN1 -> window-partitioned xln (R1, bf16)
  k_ln<<<MREAL, 256, 0, stream>>>(x_nhwc, ln1_w, ln1_b, R1, 1);
  // 3+4) per window chunk: qkv GEMM (V pre-transposed) -> rel bias -> attn
  for (int w0 = 0; w0 < NWINS; w0 += Wc) {
    int wc = NWINS - w0 < Wc ? NWINS - w0 : Wc;
    int Mc = wc * NTOK;
    k_gemm_mfma<<<dim3(18, (Mc + 127) / 128), 256, 0, stream>>>(
        R1 + (size_t)w0 * NTOK * CH, qkvT, qkv_b, R2, Vt,
        Mc, 3 * CH, CH, 0, 3, 0);
    k_relbias<<<(Mc * NHEAD + 255) / 256, 256, 0, stream>>>(
        R2, rel_h, rel_w, rhg, rwg, Mc);
    k_attn_mfma<<<dim3(NHEAD, wc), 256, 0, stream>>>(
        R2, Vt, rhg, rwg, R1, w0);
  }
  // 5) proj + window-unpartition residual add into x_nhwc
  k_gemm_mfma<<<dim3(6, (MWIN + 127) / 128), 256, 0, stream>>>(
      R1, projT, proj_b, x_nhwc, nullptr, MWIN, CH, CH, 0, 2, 0);
  // 6) LN2 -> y_ln (R1 rows 0..16383)
  k_ln<<<MREAL, 256, 0, stream>>>(x_nhwc, ln2_w, ln2_b, R1, 0);
  // 7+8) per row chunk: fc1+GELU -> R2, fc2 + residual add into x_nhwc
  for (int r0 = 0; r0 < MREAL; r0 += Rc) {
    int rc = MREAL - r0 < Rc ? MREAL - r0 : Rc;
    k_gemm_mfma<<<dim3(24, (rc + 127) / 128), 256, 0, stream>>>(
        R1 + (size_t)r0 * CH, fc1T, fc1_b, R2, nullptr, rc, MLPC, CH, 1, 0, 0);
    k_gemm_mfma<<<dim3(6, (rc + 127) / 128), 256, 0, stream>>>(
        R2, fc2T, fc2_b, x_nhwc + (size_t)r0 * CH, nullptr, rc, CH, MLPC, 0, 1, 0);
  }
  // 9) NHWC -> NCHW output
  k_nhwc2nchw<<<dim3(128, 24, NIMG), dim3(32, 8), 0, stream>>>(x_nhwc, out);
}

// Round 5
// 784.244 us; speedup vs baseline: 4.5020x; 1.2271x over previous
//
#include <hip/hip_runtime.h>
#include <cstdint>
#include <cstddef>

// Problem constants (ViTDet block, B=4, 64x64, DIM=768, 14x14 windows)
#define NIMG   4
#define GRIDSZ 64          // H = W = 64
#define CH     768
#define NHEAD  12
#define WSZ    14
#define NWINS  100         // 4 images * 5*5 windows
#define NTOK   196         // 14*14
#define MWIN   19600       // NWINS*NTOK
#define MREAL  16384       // 4*64*64
#define MLPC   3072
#define QKSCALE 0.125f

#define KSTR 72            // Ks LDS row stride (u16): 144B rows -> 2-way banks
#define VSTR 216           // Vt row stride (u16): 432B rows -> 2-way banks
#define PSTR 40            // P slice row stride (u16): 80B rows -> 2-way banks

typedef unsigned short u16;
typedef __attribute__((ext_vector_type(8))) short bf16x8;
typedef __attribute__((ext_vector_type(4))) float f32x4;

__device__ __forceinline__ float b2f(u16 u) {
  uint32_t x = (uint32_t)u << 16; float f; __builtin_memcpy(&f, &x, 4); return f;
}
__device__ __forceinline__ u16 f2b(float f) {
  uint32_t x; __builtin_memcpy(&x, &f, 4);
  x += 0x7fffu + ((x >> 16) & 1u);           // round-to-nearest-even
  return (u16)(x >> 16);
}

// async global->LDS, 16B per lane; lds base must be wave-uniform
__device__ __forceinline__ void gl_lds16(const u16* g, u16* l) {
  __builtin_amdgcn_global_load_lds(
      (const __attribute__((address_space(1))) unsigned int*)g,
      (__attribute__((address_space(3))) unsigned int*)l, 16, 0, 0);
}

// ---------------------------------------------------------------------------
// Transpose NCHW -> NHWC  (f32 -> f32), 32x32 LDS tiles
// ---------------------------------------------------------------------------
__global__ __launch_bounds__(256) void k_nchw2nhwc(const float* __restrict__ in,
                                                   float* __restrict__ out) {
  __shared__ float tile[32][33];
  int b  = blockIdx.z;
  int g0 = blockIdx.x * 32;
  int c0 = blockIdx.y * 32;
  int tx = threadIdx.x, ty = threadIdx.y;  // 32 x 8
  const float* ip = in + (size_t)b * CH * 4096;
  float* op = out + (size_t)b * 4096 * CH;
#pragma unroll
  for (int k = 0; k < 32; k += 8)
    tile[ty + k][tx] = ip[(size_t)(c0 + ty + k) * 4096 + g0 + tx];
  __syncthreads();
#pragma unroll
  for (int k = 0; k < 32; k += 8)
    op[(size_t)(g0 + ty + k) * CH + c0 + tx] = tile[tx][ty + k];
}

__global__ __launch_bounds__(256) void k_nhwc2nchw(const float* __restrict__ in,
                                                   float* __restrict__ out) {
  __shared__ float tile[32][33];
  int b  = blockIdx.z;
  int g0 = blockIdx.x * 32;
  int c0 = blockIdx.y * 32;
  int tx = threadIdx.x, ty = threadIdx.y;
  const float* ip = in + (size_t)b * 4096 * CH;
  float* op = out + (size_t)b * CH * 4096;
#pragma unroll
  for (int k = 0; k < 32; k += 8)
    tile[ty + k][tx] = ip[(size_t)(g0 + ty + k) * CH + c0 + tx];
  __syncthreads();
#pragma unroll
  for (int k = 0; k < 32; k += 8)
    op[(size_t)(c0 + ty + k) * 4096 + g0 + tx] = tile[tx][ty + k];
}

// ---------------------------------------------------------------------------
// Weight convert+transpose: in f32 [K][N] -> out bf16 [N][K]
// ---------------------------------------------------------------------------
__global__ __launch_bounds__(256) void k_wt(const float* __restrict__ in,
                                            u16* __restrict__ out,
                                            int K, int N) {
  __shared__ float t[32][33];
  int n0 = blockIdx.x * 32, k0 = blockIdx.y * 32;
  int tx = threadIdx.x, ty = threadIdx.y;  // 32 x 8
#pragma unroll
  for (int k = 0; k < 32; k += 8)
    t[ty + k][tx] = in[(size_t)(k0 + ty + k) * N + n0 + tx];
  __syncthreads();
#pragma unroll
  for (int k = 0; k < 32; k += 8)
    out[(size_t)(n0 + ty + k) * K + k0 + tx] = f2b(t[tx][ty + k]);
}

// ---------------------------------------------------------------------------
// LayerNorm over 768 channels (f32 in, bf16 out). One 256-thr block per row.
// ---------------------------------------------------------------------------
__device__ __forceinline__ float block_sum(float s, float* red) {
  __syncthreads();
#pragma unroll
  for (int off = 32; off > 0; off >>= 1) s += __shfl_down(s, off, 64);
  int wid = threadIdx.x >> 6, lane = threadIdx.x & 63;
  if (lane == 0) red[wid] = s;
  __syncthreads();
  return red[0] + red[1] + red[2] + red[3];
}

__global__ __launch_bounds__(256) void k_ln(const float* __restrict__ x,
                                            const float* __restrict__ wt,
                                            const float* __restrict__ bs,
                                            u16* __restrict__ y,
                                            int window_mode) {
  __shared__ float red[4];
  int row = blockIdx.x, tid = threadIdx.x;
  const float* xp = x + (size_t)row * CH;
  float v0 = xp[tid], v1 = xp[tid + 256], v2 = xp[tid + 512];
  float mu = block_sum(v0 + v1 + v2, red) * (1.0f / 768.0f);
  float d0 = v0 - mu, d1 = v1 - mu, d2 = v2 - mu;
  float var = block_sum(d0 * d0 + d1 * d1 + d2 * d2, red) * (1.0f / 768.0f);
  float rs = rsqrtf(var + 1e-6f);
  int orow = row;
  if (window_mode) {
    int b = row >> 12, hw = row & 4095;
    int h = hw >> 6, wc = hw & 63;
    orow = (b * 25 + (h / WSZ) * 5 + (wc / WSZ)) * NTOK + (h % WSZ) * WSZ + (wc % WSZ);
  }
  u16* yp = y + (size_t)orow * CH;
  yp[tid]       = f2b(d0 * rs * wt[tid]       + bs[tid]);
  yp[tid + 256] = f2b(d1 * rs * wt[tid + 256] + bs[tid + 256]);
  yp[tid + 512] = f2b(d2 * rs * wt[tid + 512] + bs[tid + 512]);
}

// ---------------------------------------------------------------------------
// bf16 MFMA GEMM: C = act(A[MxK] @ BT[NxK]^T + bias), fp32 accumulate.
// 128x128 tile, BK=64 as two 128x32 slabs (one barrier pair per 64 k),
// 256 thr (4 waves, each 64x64 via 4x4 mfma 16x16x32).
// Operand-swapped mfma(b,a): thread holds 4 CONSECUTIVE COLUMNS of one row
// (row = wm+mi*16+l15, cols = wn+ni*16+quad*4+r) -> packed 8B/16B stores.
// mode 0: C bf16 store   mode 1: C f32 +=   mode 2: window-unpartition f32 +=
// mode 3: qkv split: cols<1536 -> C bf16; V cols -> Vt[(wloc*12+h)*64+d][tok]
// act 1: exact GELU.  Requires N%128==0, K%64==0.
// ---------------------------------------------------------------------------
__global__ __launch_bounds__(256) void k_gemm_mfma(const u16* __restrict__ A,
                                                   const u16* __restrict__ BT,
                                                   const float* __restrict__ bias,
                                                   void* __restrict__ Cv,
                                                   u16* __restrict__ Vt,
                                                   int M, int N, int K,
                                                   int act, int mode, int row0) {
  __shared__ u16 As[2][128 * 32];
  __shared__ u16 Bs[2][128 * 32];
  int tid  = threadIdx.x;
  int lane = tid & 63, wave = tid >> 6;
  int bn = blockIdx.x, bm = blockIdx.y;
  int wm = (wave & 1) * 64, wn = (wave >> 1) * 64;
  int l15 = lane & 15, quad = lane >> 4;

  f32x4 acc[4][4];   // acc[mi][ni]: rows wm+mi*16+l15, cols wn+ni*16+quad*4+r
#pragma unroll
  for (int i = 0; i < 4; i++)
#pragma unroll
    for (int j = 0; j < 4; j++) acc[i][j] = (f32x4){0.f, 0.f, 0.f, 0.f};

  const u16* Atile = A + (size_t)bm * 128 * K;
  const u16* Btile = BT + (size_t)bn * 128 * K;

  // staging (per 32-k slab): chunk c = row*4 + 16B-part; threads cover 512
  int c0 = wave * 64 + lane;
  int c1 = c0 + 256;
  int ar0 = c0 >> 2, ao0 = (c0 & 3) * 8;
  int ar1 = c1 >> 2, ao1 = (c1 & 3) * 8;
  int lo0 = (wave * 64) * 8;          // wave-uniform LDS element offsets
  int lo1 = (256 + wave * 64) * 8;

  for (int k0 = 0; k0 < K; k0 += 64) {
    __syncthreads();
#pragma unroll
    for (int s = 0; s < 2; s++) {
      int kk = k0 + s * 32;
      gl_lds16(Atile + (size_t)ar0 * K + kk + ao0, &As[s][lo0]);
      gl_lds16(Atile + (size_t)ar1 * K + kk + ao1, &As[s][lo1]);
      gl_lds16(Btile + (size_t)ar0 * K + kk + ao0, &Bs[s][lo0]);
      gl_lds16(Btile + (size_t)ar1 * K + kk + ao1, &Bs[s][lo1]);
    }
    __syncthreads();
#pragma unroll
    for (int s = 0; s < 2; s++) {
      bf16x8 af[4], bfv[4];
#pragma unroll
      for (int mi = 0; mi < 4; mi++)
        af[mi] = *(const bf16x8*)&As[s][(size_t)(wm + mi * 16 + l15) * 32 + quad * 8];
#pragma unroll
      for (int ni = 0; ni < 4; ni++)
        bfv[ni] = *(const bf16x8*)&Bs[s][(size_t)(wn + ni * 16 + l15) * 32 + quad * 8];
#pragma unroll
      for (int mi = 0; mi < 4; mi++)
#pragma unroll
        for (int ni = 0; ni < 4; ni++)
          acc[mi][ni] = __builtin_amdgcn_mfma_f32_16x16x32_bf16(
              bfv[ni], af[mi], acc[mi][ni], 0, 0, 0);   // swapped: D = C^T layout
    }
  }

  // epilogue: row = bm*128+wm+mi*16+l15 ; cols = bn*128+wn+ni*16+quad*4+r
#pragma unroll
  for (int mi = 0; mi < 4; mi++) {
    int row = bm * 128 + wm + mi * 16 + l15;
    if (row >= M) continue;
    size_t gbase = 0;
    bool valid = true;
    int wloc = 0, tok = 0;
    if (mode == 2) {  // window slot -> image token (skip pad)
      int rowa = row + row0;
      int widx = rowa / NTOK, tt = rowa % NTOK;
      int b = widx / 25, wq = widx % 25;
      int h = (wq / 5) * WSZ + tt / WSZ;
      int w = (wq % 5) * WSZ + tt % WSZ;
      valid = (h < GRIDSZ) && (w < GRIDSZ);
      gbase = valid ? ((size_t)((b * GRIDSZ + h) * GRIDSZ + w)) * CH : 0;
    }
    if (mode == 3) { wloc = row / NTOK; tok = row - wloc * NTOK; }
#pragma unroll
    for (int ni = 0; ni < 4; ni++) {
      int colb = bn * 128 + wn + ni * 16 + quad * 4;
      float4 b4 = *(const float4*)&bias[colb];
      float v[4] = {acc[mi][ni][0] + b4.x, acc[mi][ni][1] + b4.y,
                    acc[mi][ni][2] + b4.z, acc[mi][ni][3] + b4.w};
      if (act == 1) {
#pragma unroll
        for (int r = 0; r < 4; r++)
          v[r] = 0.5f * v[r] * (1.0f + erff(v[r] * 0.70710678118654752440f));
      }
      if (mode == 0) {
        ushort4 st = make_ushort4(f2b(v[0]), f2b(v[1]), f2b(v[2]), f2b(v[3]));
        *(ushort4*)((u16*)Cv + (size_t)row * N + colb) = st;
      } else if (mode == 1) {
        float4* p = (float4*)((float*)Cv + (size_t)row * N + colb);
        float4 o = *p;
        o.x += v[0]; o.y += v[1]; o.z += v[2]; o.w += v[3];
        *p = o;
      } else if (mode == 2) {
        if (valid) {
          float4* p = (float4*)((float*)Cv + gbase + colb);
          float4 o = *p;
          o.x += v[0]; o.y += v[1]; o.z += v[2]; o.w += v[3];
          *p = o;
        }
      } else {  // mode 3
        if (colb < 1536) {
          ushort4 st = make_ushort4(f2b(v[0]), f2b(v[1]), f2b(v[2]), f2b(v[3]));
          *(ushort4*)((u16*)Cv + (size_t)row * N + colb) = st;
        } else {
          int vv = colb - 1536, hd = vv >> 6, d = vv & 63;
          u16* vp = Vt + ((size_t)(wloc * NHEAD + hd) * 64 + d) * VSTR + tok;
#pragma unroll
          for (int r = 0; r < 4; r++) vp[(size_t)r * VSTR] = f2b(v[r]);
        }
      }
    }
  }
}

// ---------------------------------------------------------------------------
// Rel-pos bias tables from UNSCALED q: rhg/rwg[(wloc*12+head)*196+tok][16]
// (kk 0..13 valid). One thread per (row, head).
// ---------------------------------------------------------------------------
__global__ __launch_bounds__(256) void k_relbias(const u16* __restrict__ qkv,
                                                 const float* __restrict__ rel_h,
                                                 const float* __restrict__ rel_w,
                                                 u16* __restrict__ rhg,
                                                 u16* __restrict__ rwg,
                                                 int nrows) {
  int idx = blockIdx.x * 256 + threadIdx.x;
  if (idx >= nrows * NHEAD) return;
  int head = idx % NHEAD, row = idx / NHEAD;
  int wloc = row / NTOK, tok = row - wloc * NTOK;
  const u16* qp = qkv + (size_t)row * (3 * CH) + head * 64;
  float q[64];
#pragma unroll
  for (int d = 0; d < 64; d += 4) {
    ushort4 u4 = *(const ushort4*)(qp + d);
    q[d] = b2f(u4.x); q[d + 1] = b2f(u4.y); q[d + 2] = b2f(u4.z); q[d + 3] = b2f(u4.w);
  }
  int hq = tok / WSZ, wq = tok % WSZ;
  size_t obase = ((size_t)(wloc * NHEAD + head) * NTOK + tok) * 16;
  for (int kk = 0; kk < WSZ; kk++) {
    const float* rh = rel_h + (size_t)(hq - kk + WSZ - 1) * 64;
    const float* rw = rel_w + (size_t)(wq - kk + WSZ - 1) * 64;
    float sh = 0.0f, sw = 0.0f;
#pragma unroll
    for (int d = 0; d < 64; d++) { sh += q[d] * rh[d]; sw += q[d] * rw[d]; }
    rhg[obase + kk] = f2b(sh);
    rwg[obase + kk] = f2b(sw);
  }
}

// ---------------------------------------------------------------------------
// MFMA windowed attention. One block per (head, local window), 4 waves.
// Ks: [196][KSTR] row-major bf16.  Vs: V^T [64][VSTR] bf16 (from global Vt).
// Wave handles Q row-tiles {w, w+4, w+8, (w==0:12)}. S = Q K^T via mfma;
// exp-sum softmax (no max-sub; scores bounded); P -> per-wave LDS slice ->
// A-frag; O = P V via mfma with V^T B-frags. Cols>=196 masked to p=0.
// ---------------------------------------------------------------------------
__global__ __launch_bounds__(256) void k_attn_mfma(const u16* __restrict__ qkv,
                                                   const u16* __restrict__ Vt,
                                                   const u16* __restrict__ rhg,
                                                   const u16* __restrict__ rwg,
                                                   u16* __restrict__ out,
                                                   int win0) {
  __shared__ u16 Ks[NTOK * KSTR];        // 28224 B
  __shared__ u16 Vs[64 * VSTR];          // 27648 B
  __shared__ u16 Ps[4][16 * PSTR];       // 5120 B   (total 60992 B)
  int head = blockIdx.x, wloc = blockIdx.y;
  int tid = threadIdx.x, lane = tid & 63, wave = tid >> 6;
  int l15 = lane & 15, quad = lane >> 4;
  const u16* qbase = qkv + (size_t)wloc * NTOK * (3 * CH) + head * 64;

  // stage K rows (196 x 64) -> Ks stride 72
  for (int c = tid; c < NTOK * 8; c += 256) {
    int tok = c >> 3, part = c & 7;
    uint4 v = *(const uint4*)(qbase + (size_t)tok * (3 * CH) + CH + part * 8);
    *(uint4*)&Ks[tok * KSTR + part * 8] = v;
  }
  // stage V^T (64 x VSTR, layout-identical in global) via global_load_lds
  const u16* vb = Vt + (size_t)(wloc * NHEAD + head) * 64 * VSTR;
#pragma unroll
  for (int it = 0; it < 7; ++it) {
    int c = it * 256 + tid;
    if (c < 64 * VSTR / 8) gl_lds16(vb + (size_t)c * 8, Vs + ((size_t)it * 256 + wave * 64) * 8);
  }
  __syncthreads();

  const u16* rhp = rhg + ((size_t)(wloc * NHEAD + head) * NTOK) * 16;
  const u16* rwp = rwg + ((size_t)(wloc * NHEAD + head) * NTOK) * 16;
  int winabs = win0 + wloc;

  for (int t16 = wave; t16 < 13; t16 += 4) {
    // Q A-frags (row = l15, k = quad*8..)
    int qtok = t16 * 16 + l15; if (qtok > NTOK - 1) qtok = NTOK - 1;
    bf16x8 aq0 = *(const bf16x8*)(qbase + (size_t)qtok * (3 * CH) + quad * 8);
    bf16x8 aq1 = *(const bf16x8*)(qbase + (size_t)qtok * (3 * CH) + 32 + quad * 8);

    f32x4 s[13];
#pragma unroll
    for (int ct = 0; ct < 13; ct++) s[ct] = (f32x4){0.f, 0.f, 0.f, 0.f};
#pragma unroll
    for (int ct = 0; ct < 13; ct++) {
      int ktok = ct * 16 + l15; if (ktok > NTOK - 1) ktok = NTOK - 1;
      bf16x8 bk0 = *(const bf16x8*)&Ks[ktok * KSTR + quad * 8];
      bf16x8 bk1 = *(const bf16x8*)&Ks[ktok * KSTR + 32 + quad * 8];
      s[ct] = __builtin_amdgcn_mfma_f32_16x16x32_bf16(aq0, bk0, s[ct], 0, 0, 0);
      s[ct] = __builtin_amdgcn_mfma_f32_16x16x32_bf16(aq1, bk1, s[ct], 0, 0, 0);
    }

    f32x4 o[4];
#pragma unroll
    for (int ni = 0; ni < 4; ni++) o[ni] = (f32x4){0.f, 0.f, 0.f, 0.f};
    float lsum[4] = {0.f, 0.f, 0.f, 0.f};
    int row0t = t16 * 16 + quad * 4;

#pragma unroll
    for (int cc = 0; cc < 7; ++cc) {
#pragma unroll
      for (int half = 0; half < 2; ++half) {
        int ct = cc * 2 + half;
        if (ct < 13) {
          int col = ct * 16 + l15;
          int jh = col / WSZ, jw = col - jh * WSZ;
          bool colok = col < NTOK;
#pragma unroll
          for (int r = 0; r < 4; r++) {
            int rowt = row0t + r; int rowc = rowt > NTOK - 1 ? NTOK - 1 : rowt;
            float bias = b2f(rhp[rowc * 16 + jh]) + b2f(rwp[rowc * 16 + jw]);
            float sv = s[ct][r] * QKSCALE + bias;
            float p = colok ? __expf(sv) : 0.f;
            lsum[r] += p;
            Ps[wave][(quad * 4 + r) * PSTR + half * 16 + l15] = f2b(p);
          }
        } else {
#pragma unroll
          for (int r = 0; r < 4; r++)
            Ps[wave][(quad * 4 + r) * PSTR + half * 16 + l15] = 0;
        }
      }
      // wave-local LDS round-trip: P C-layout -> A-frag layout
      bf16x8 pa = *(const bf16x8*)&Ps[wave][l15 * PSTR + quad * 8];
#pragma unroll
      for (int ni = 0; ni < 4; ni++) {
        bf16x8 bv = *(const bf16x8*)&Vs[(ni * 16 + l15) * VSTR + cc * 32 + quad * 8];
        o[ni] = __builtin_amdgcn_mfma_f32_16x16x32_bf16(pa, bv, o[ni], 0, 0, 0);
      }
    }

    // row-sum reduce across the 16 lanes holding each row's columns
#pragma unroll
    for (int r = 0; r < 4; r++) {
#pragma unroll
      for (int m = 1; m < 16; m <<= 1) lsum[r] += __shfl_xor(lsum[r], m, 64);
    }

#pragma unroll
    for (int r = 0; r < 4; r++) {
      int rowt = row0t + r;
      if (rowt < NTOK) {
        float inv = 1.0f / lsum[r];
        u16* op = out + ((size_t)winabs * NTOK + rowt) * CH + head * 64;
#pragma unroll
        for (int ni = 0; ni < 4; ni++) op[ni * 16 + l15] = f2b(o[ni][r] * inv);
      }
    }
  }
}

// ---------------------------------------------------------------------------
extern "C" void kernel_launch(void* const* d_in, const int* in_sizes, int n_in,
                              void* d_out, int out_size, void* d_ws, size_t ws_size,
                              hipStream_t stream) {
  const float* hidden = (const float*)d_in[0];
  const float* ln1_w  = (const float*)d_in[1];
  const float* ln1_b  = (const float*)d_in[2];
  const float* qkv_w  = (const float*)d_in[3];
  const float* qkv_b  = (const float*)d_in[4];
  const float* proj_w = (const float*)d_in[5];
  const float* proj_b = (const float*)d_in[6];
  const float* rel_h  = (const float*)d_in[7];
  const float* rel_w  = (const float*)d_in[8];
  const float* ln2_w  = (const float*)d_in[9];
  const float* ln2_b  = (const float*)d_in[10];
  const float* fc1_w  = (const float*)d_in[11];
  const float* fc1_b  = (const float*)d_in[12];
  const float* fc2_w  = (const float*)d_in[13];
  const float* fc2_b  = (const float*)d_in[14];
  float* out = (float*)d_out;

  // Workspace layout (bytes):
  //   x_nhwc f32 : 50,331,648   (residual accumulator)
  //   R1 bf16    : 30,105,600   (19600x768: xln -> attn_out -> y_ln)
  //   WT bf16    : 14,155,776   (qkv_wT | proj_wT | fc1_wT | fc2_wT)
  //   R2 bf16    : remainder    (per-chunk: qkv | Vt | rhg | rwg ; or mlp-h)
  char* ws = (char*)d_ws;
  float* x_nhwc = (float*)ws;
  u16*   R1     = (u16*)(ws + 50331648);
  u16*   qkvT   = (u16*)(ws + 80437248);
  u16*   projT  = qkvT + (size_t)2304 * 768;
  u16*   fc1T   = projT + (size_t)768 * 768;
  u16*   fc2T   = fc1T + (size_t)3072 * 768;
  u16*   R2     = fc2T + (size_t)768 * 3072;
  size_t used   = (size_t)80437248 + 14155776;
  size_t r2e    = ws_size > used ? (ws_size - used) >> 1 : 0;  // bf16 elems

  // per-window footprint in R2: qkv rows + Vt + rhg + rwg
  const size_t PW_QKV = (size_t)NTOK * 3 * CH;            // 451584
  const size_t PW_VT  = (size_t)NHEAD * 64 * VSTR;        // 165888
  const size_t PW_RB  = (size_t)NHEAD * NTOK * 16;        // 37632 (x2 tables)
  const size_t perwin = PW_QKV + PW_VT + 2 * PW_RB;       // 692736 elems
  size_t wc_s = r2e / perwin;
  int Wc = wc_s >= NWINS ? NWINS : (int)wc_s;
  if (Wc < 1) Wc = 1;
  size_t rc_s = (r2e / MLPC / 128) * 128;
  int Rc = rc_s >= MREAL ? MREAL : (int)rc_s;
  if (Rc < 128) Rc = 128;

  u16* Vt  = R2 + (size_t)Wc * PW_QKV;
  u16* rhg = Vt + (size_t)Wc * PW_VT;
  u16* rwg = rhg + (size_t)Wc * PW_RB;

  // 0) weight convert + transpose (f32 [K][N] -> bf16 [N][K])
  k_wt<<<dim3(72, 24), dim3(32, 8), 0, stream>>>(qkv_w, qkvT, CH, 3 * CH);
  k_wt<<<dim3(24, 24), dim3(32, 8), 0, stream>>>(proj_w, projT, CH, CH);
  k_wt<<<dim3(96, 24), dim3(32, 8), 0, stream>>>(fc1_w, fc1T, CH, MLPC);
  k_wt<<<dim3(24, 96), dim3(32, 8), 0, stream>>>(fc2_w, fc2T, MLPC, CH);

  // zero window buffer so pad tokens are exact zeros before qkv GEMM
  hipMemsetAsync(R1, 0, (size_t)MWIN * CH * sizeof(u16), stream);

  // 1) NCHW -> NHWC (shortcut copy)
  k_nchw2nhwc<<<dim3(128, 24, NIMG), dim3(32, 8), 0, stream>>>(hidden, x_nhwc);
  // 2) LN1 -> window-partitioned xln (R1, bf16)
  k_ln<<<MREAL, 256, 0, stream>>>(x_nhwc, ln1_w, ln1_b, R1, 1);
  // 3+4) per window chunk: qkv GEMM (V pre-transposed) -> rel bias -> attn
  for (int w0 = 0; w0 < NWINS; w0 += Wc) {
    int wc = NWINS - w0 < Wc ? NWINS - w0 : Wc;
    int Mc = wc * NTOK;
    k_gemm_mfma<<<dim3(18, (Mc + 127) / 128), 256, 0, stream>>>(
        R1 + (size_t)w0 * NTOK * CH, qkvT, qkv_b, R2, Vt,
        Mc, 3 * CH, CH, 0, 3, 0);
    k_relbias<<<(Mc * NHEAD + 255) / 256, 256, 0, stream>>>(
        R2, rel_h, rel_w, rhg, rwg, Mc);
    k_attn_mfma<<<dim3(NHEAD, wc), 256, 0, stream>>>(
        R2, Vt, rhg, rwg, R1, w0);
  }
  // 5) proj + window-unpartition residual add into x_nhwc
  k_gemm_mfma<<<dim3(6, (MWIN + 127) / 128), 256, 0, stream>>>(
      R1, projT, proj_b, x_nhwc, nullptr, MWIN, CH, CH, 0, 2, 0);
  // 6) LN2 -> y_ln (R1 rows 0..16383)
  k_ln<<<MREAL, 256, 0, stream>>>(x_nhwc, ln2_w, ln2_b, R1, 0);
  // 7+8) per row chunk: fc1+GELU -> R2, fc2 + residual add into x_nhwc
  for (int r0 = 0; r0 < MREAL; r0 += Rc) {
    int rc = MREAL - r0 < Rc ? MREAL - r0 : Rc;
    k_gemm_mfma<<<dim3(24, (rc + 127) / 128), 256, 0, stream>>>(
        R1 + (size_t)r0 * CH, fc1T, fc1_b, R2, nullptr, rc, MLPC, CH, 1, 0, 0);
    k_gemm_mfma<<<dim3(6, (rc + 127) / 128), 256, 0, stream>>>(
        R2, fc2T, fc2_b, x_nhwc + (size_t)r0 * CH, nullptr, rc, CH, MLPC, 0, 1, 0);
  }
  // 9) NHWC -> NCHW output
  k_nhwc2nchw<<<dim3(128, 24, NIMG), dim3(32, 8), 0, stream>>>(x_nhwc, out);
}